// Round 1
// baseline (232.787 us; speedup 1.0000x reference)
//
#include <hip/hip_runtime.h>
#include <hip/hip_fp16.h>

using i32x4  = __attribute__((ext_vector_type(4)))  int;
using i32x16 = __attribute__((ext_vector_type(16))) int;

static constexpr int M  = 4 * 2048;   // 8192 rows (B*S)
static constexpr int N  = 4096;       // OUT_F
static constexpr int K  = 4096;       // IN_F
static constexpr int BM = 128, BN = 128, BK = 64;
static constexpr int NT = K / BK;     // 64 K-tiles
static constexpr int TILE = BM * BK;  // 8192 bytes per packed int8 tile

// ---------------- pack kernels: int32 -> blocked int8 tiles in d_ws ----------
// tile layout (8 KB): [kg(4)][row(128)][16 bytes of k]  -> byte off = kg*2048 + row*16 + b
// wa: [M/128][NT][tile], wb: [N/128][NT][tile] (wb is W transposed: granule bytes walk k)

__device__ __forceinline__ unsigned pack4(i32x4 v) {
  return (unsigned)((v.x & 255) | ((v.y & 255) << 8) | ((v.z & 255) << 16) | (v.w << 24));
}

__global__ __launch_bounds__(256) void pack_x_kernel(const int* __restrict__ x,
                                                     unsigned char* __restrict__ wa) {
  unsigned g = blockIdx.x * 256 + threadIdx.x;     // dest 16B granule id, < M*K/16
  unsigned tile = g >> 9, gt = g & 511;
  unsigned kg = gt >> 7, row = gt & 127;
  unsigned br = tile >> 6, kt = tile & 63;
  const int* src = x + ((size_t)(br * 128 + row) * K + kt * 64 + kg * 16);
  i32x4 v0 = *(const i32x4*)(src + 0);
  i32x4 v1 = *(const i32x4*)(src + 4);
  i32x4 v2 = *(const i32x4*)(src + 8);
  i32x4 v3 = *(const i32x4*)(src + 12);
  i32x4 d;
  d.x = (int)pack4(v0); d.y = (int)pack4(v1); d.z = (int)pack4(v2); d.w = (int)pack4(v3);
  *(i32x4*)(wa + (size_t)g * 16) = d;
}

__global__ __launch_bounds__(256) void pack_w_kernel(const int* __restrict__ w,
                                                     unsigned char* __restrict__ wb) {
  unsigned g = blockIdx.x * 256 + threadIdx.x;     // dest 16B granule id, < N*K/16
  unsigned tile = g >> 9, gt = g & 511;
  unsigned kg = gt >> 7, col = gt & 127;
  unsigned bn = tile >> 6, kt = tile & 63;
  unsigned n  = bn * 128 + col;
  unsigned k0 = kt * 64 + kg * 16;
  const int* src = w + (size_t)k0 * N + n;
  i32x4 d;
#pragma unroll
  for (int j = 0; j < 4; ++j) {
    int b0 = src[(size_t)(j * 4 + 0) * N];
    int b1 = src[(size_t)(j * 4 + 1) * N];
    int b2 = src[(size_t)(j * 4 + 2) * N];
    int b3 = src[(size_t)(j * 4 + 3) * N];
    d[j] = (b0 & 255) | ((b1 & 255) << 8) | ((b2 & 255) << 16) | (b3 << 24);
  }
  *(i32x4*)(wb + (size_t)g * 16) = d;
}

// ---------------- GEMM: int8 MFMA, double-buffered LDS, global_load_lds -----

__device__ __forceinline__ void gload_lds16(const void* g, void* l) {
  __builtin_amdgcn_global_load_lds((const __attribute__((address_space(1))) unsigned int*)g,
                                   (__attribute__((address_space(3))) unsigned int*)l,
                                   16, 0, 0);
}

__global__ __launch_bounds__(256) void gemm_i8(const unsigned char* __restrict__ wa,
                                               const unsigned char* __restrict__ wb,
                                               const __half* __restrict__ bias,
                                               const float* __restrict__ alphaP,
                                               float* __restrict__ out) {
  __shared__ __align__(16) unsigned char As[2][TILE];
  __shared__ __align__(16) unsigned char Bs[2][TILE];

  const int tid  = threadIdx.x;
  const int lane = tid & 63;
  const int w    = tid >> 6;        // wave 0..3
  const int wr   = w >> 1, wc = w & 1;
  const int bc   = blockIdx.x, br = blockIdx.y;

  const unsigned char* ga = wa + (size_t)br * NT * TILE;
  const unsigned char* gb = wb + (size_t)bc * NT * TILE;

  i32x16 acc[2][2] = {};

  const int l31 = lane & 31;
  const int kgl = lane >> 5;        // which 16-byte k-group within a 32-k chunk

  auto stage = [&](int buf, int t) {
    const unsigned char* at = ga + (size_t)t * TILE;
    const unsigned char* bt = gb + (size_t)t * TILE;
#pragma unroll
    for (int i = 0; i < 2; ++i) {
      const int seg = w * 2 + i;    // 8 segments of 1 KB each per tile
      gload_lds16(at + seg * 1024 + lane * 16, &As[buf][seg * 1024]);
      gload_lds16(bt + seg * 1024 + lane * 16, &Bs[buf][seg * 1024]);
    }
  };

  stage(0, 0);
  asm volatile("s_waitcnt vmcnt(0)" ::: "memory");
  __syncthreads();

  int cur = 0;
  for (int t = 0; t < NT; ++t) {
    if (t + 1 < NT) stage(cur ^ 1, t + 1);   // prefetch next tile (other buffer)
#pragma unroll
    for (int c = 0; c < 2; ++c) {            // two 32-k chunks per BK=64
      const int kg = c * 2 + kgl;
      const unsigned char* Ap = &As[cur][kg * 2048];
      const unsigned char* Bp = &Bs[cur][kg * 2048];
      i32x4 a0 = *(const i32x4*)(Ap + (wr * 64 + l31) * 16);
      i32x4 a1 = *(const i32x4*)(Ap + (wr * 64 + 32 + l31) * 16);
      i32x4 b0 = *(const i32x4*)(Bp + (wc * 64 + l31) * 16);
      i32x4 b1 = *(const i32x4*)(Bp + (wc * 64 + 32 + l31) * 16);
      acc[0][0] = __builtin_amdgcn_mfma_i32_32x32x32_i8(a0, b0, acc[0][0], 0, 0, 0);
      acc[0][1] = __builtin_amdgcn_mfma_i32_32x32x32_i8(a0, b1, acc[0][1], 0, 0, 0);
      acc[1][0] = __builtin_amdgcn_mfma_i32_32x32x32_i8(a1, b0, acc[1][0], 0, 0, 0);
      acc[1][1] = __builtin_amdgcn_mfma_i32_32x32x32_i8(a1, b1, acc[1][1], 0, 0, 0);
    }
    asm volatile("s_waitcnt vmcnt(0)" ::: "memory");
    __syncthreads();
    cur ^= 1;
  }

  // epilogue: C/D layout col=lane&31, row=(r&3)+8*(r>>2)+4*(lane>>5)
  const float alpha = *alphaP;
  const int row0 = br * 128 + wr * 64 + 4 * kgl;
  const int col0 = bc * 128 + wc * 64 + l31;
#pragma unroll
  for (int ni = 0; ni < 2; ++ni) {
    const int col = col0 + ni * 32;
    const float bf = __half2float(bias[col]);
#pragma unroll
    for (int mi = 0; mi < 2; ++mi) {
#pragma unroll
      for (int r = 0; r < 16; ++r) {
        const int row = row0 + mi * 32 + (r & 3) + 8 * (r >> 2);
        out[(size_t)row * N + col] = ((float)acc[mi][ni][r] + bf) * alpha;
      }
    }
  }
}

extern "C" void kernel_launch(void* const* d_in, const int* in_sizes, int n_in,
                              void* d_out, int out_size, void* d_ws, size_t ws_size,
                              hipStream_t stream) {
  const int*    x     = (const int*)d_in[0];
  const int*    wgt   = (const int*)d_in[1];
  const __half* bias  = (const __half*)d_in[2];
  const float*  alpha = (const float*)d_in[3];
  float*        out   = (float*)d_out;

  // workspace: packed A (32 MB) + packed B (16 MB) = 48 MB
  unsigned char* wa = (unsigned char*)d_ws;
  unsigned char* wb = wa + (size_t)M * K;

  pack_x_kernel<<<(M * (size_t)K / 16) / 256, 256, 0, stream>>>(x, wa);
  pack_w_kernel<<<(N * (size_t)K / 16) / 256, 256, 0, stream>>>(wgt, wb);

  dim3 grid(N / BN, M / BM);
  gemm_i8<<<grid, 256, 0, stream>>>(wa, wb, bias, alpha, out);
}

// Round 2
// 231.316 us; speedup vs baseline: 1.0064x; 1.0064x over previous
//
#include <hip/hip_runtime.h>
#include <hip/hip_fp16.h>

using i32x4  = __attribute__((ext_vector_type(4)))  int;
using i32x16 = __attribute__((ext_vector_type(16))) int;

static constexpr int M  = 4 * 2048;   // 8192 rows (B*S)
static constexpr int N  = 4096;       // OUT_F
static constexpr int K  = 4096;       // IN_F
static constexpr int BM = 256, BN = 256, BK = 64;
static constexpr int NT = K / BK;       // 64 K-tiles
static constexpr int TILE = BM * BK;    // 16384 bytes per packed int8 tile

// ---------------- pack kernels: int32 -> blocked int8 tiles in d_ws ----------
// tile layout (16 KB): [kg(4)][row(256)][16 bytes of k] -> off = kg*4096 + row*16
// wa: [M/256][NT][tile], wb: [N/256][NT][tile] (wb transposed: granule bytes walk k)

__device__ __forceinline__ unsigned pack4(i32x4 v) {
  return (unsigned)((v.x & 255) | ((v.y & 255) << 8) | ((v.z & 255) << 16) | (v.w << 24));
}

__global__ __launch_bounds__(256) void pack_x_kernel(const int* __restrict__ x,
                                                     unsigned char* __restrict__ wa) {
  unsigned g = blockIdx.x * 256 + threadIdx.x;   // dest 16B granule id, < M*K/16
  unsigned row = g & 255;
  unsigned kg  = (g >> 8) & 3;
  unsigned kt  = (g >> 10) & 63;
  unsigned br  = g >> 16;
  const int* src = x + ((size_t)(br * 256 + row) * K + kt * 64 + kg * 16);
  i32x4 v0 = *(const i32x4*)(src + 0);
  i32x4 v1 = *(const i32x4*)(src + 4);
  i32x4 v2 = *(const i32x4*)(src + 8);
  i32x4 v3 = *(const i32x4*)(src + 12);
  i32x4 d;
  d.x = (int)pack4(v0); d.y = (int)pack4(v1); d.z = (int)pack4(v2); d.w = (int)pack4(v3);
  *(i32x4*)(wa + (size_t)g * 16) = d;
}

__global__ __launch_bounds__(256) void pack_w_kernel(const int* __restrict__ w,
                                                     unsigned char* __restrict__ wb) {
  unsigned g = blockIdx.x * 256 + threadIdx.x;   // dest 16B granule id, < N*K/16
  unsigned col = g & 255;
  unsigned kg  = (g >> 8) & 3;
  unsigned kt  = (g >> 10) & 63;
  unsigned bn  = g >> 16;
  unsigned n   = bn * 256 + col;
  unsigned k0  = kt * 64 + kg * 16;
  const int* src = w + (size_t)k0 * N + n;
  i32x4 d;
#pragma unroll
  for (int j = 0; j < 4; ++j) {
    int b0 = src[(size_t)(j * 4 + 0) * N];
    int b1 = src[(size_t)(j * 4 + 1) * N];
    int b2 = src[(size_t)(j * 4 + 2) * N];
    int b3 = src[(size_t)(j * 4 + 3) * N];
    d[j] = (b0 & 255) | ((b1 & 255) << 8) | ((b2 & 255) << 16) | (b3 << 24);
  }
  *(i32x4*)(wb + (size_t)g * 16) = d;
}

// ---------------- GEMM: 256x256 tile, triple-buffered LDS, counted vmcnt ----

__device__ __forceinline__ void gload_lds16(const void* g, void* l) {
  __builtin_amdgcn_global_load_lds((const __attribute__((address_space(1))) unsigned int*)g,
                                   (__attribute__((address_space(3))) unsigned int*)l,
                                   16, 0, 0);
}

#define FENCE()   asm volatile("" ::: "memory")
#define BARRIER() do { FENCE(); __builtin_amdgcn_s_barrier(); FENCE(); } while (0)

__global__ __launch_bounds__(512, 2) void gemm_i8(const unsigned char* __restrict__ wa,
                                                  const unsigned char* __restrict__ wb,
                                                  const __half* __restrict__ bias,
                                                  const float* __restrict__ alphaP,
                                                  float* __restrict__ out) {
  __shared__ __align__(16) unsigned char As[3][TILE];
  __shared__ __align__(16) unsigned char Bs[3][TILE];

  const int tid  = threadIdx.x;
  const int lane = tid & 63;
  const int w    = tid >> 6;            // wave 0..7
  const int wr   = w >> 2, wc = w & 3;  // 2 x 4 wave grid; wave tile 128x64
  const int l31  = lane & 31;
  const int kgl  = lane >> 5;

  // XCD-aware swizzle: nwg=512 (%8==0), chunk=64; bc fast so neighbors share A
  const int bid = blockIdx.x;
  const int swz = (bid & 7) * 64 + (bid >> 3);
  const int bc  = swz & 15;             // N/256 = 16
  const int br  = swz >> 4;             // M/256 = 32

  const unsigned char* ga = wa + (size_t)br * NT * TILE;
  const unsigned char* gb = wb + (size_t)bc * NT * TILE;

  auto stage = [&](int buf, int t) {
    const unsigned char* at = ga + (size_t)t * TILE;
    const unsigned char* bt = gb + (size_t)t * TILE;
    gload_lds16(at + w * 1024 + lane * 16,        &As[buf][w * 1024]);
    gload_lds16(at + 8192 + w * 1024 + lane * 16, &As[buf][8192 + w * 1024]);
    gload_lds16(bt + w * 1024 + lane * 16,        &Bs[buf][w * 1024]);
    gload_lds16(bt + 8192 + w * 1024 + lane * 16, &Bs[buf][8192 + w * 1024]);
  };

  stage(0, 0);
  stage(1, 1);
  stage(2, 2);

  i32x16 acc[4][2] = {};

  int buf = 0;
  for (int t = 0; t < NT; ++t) {
    // wait for tile t's 4 loads; keep later tiles' loads in flight (never 0 mid-loop)
    if (t + 2 < NT)      asm volatile("s_waitcnt vmcnt(8)" ::: "memory");
    else if (t + 1 < NT) asm volatile("s_waitcnt vmcnt(4)" ::: "memory");
    else                 asm volatile("s_waitcnt vmcnt(0)" ::: "memory");
    BARRIER();                           // tile t resident for ALL waves

    i32x4 a[2][4], b[2][2];
#pragma unroll
    for (int kc = 0; kc < 2; ++kc) {
      const int kg = kc * 2 + kgl;
      const unsigned char* Ap = &As[buf][kg * 4096];
      const unsigned char* Bp = &Bs[buf][kg * 4096];
#pragma unroll
      for (int mi = 0; mi < 4; ++mi)
        a[kc][mi] = *(const i32x4*)(Ap + (wr * 128 + mi * 32 + l31) * 16);
#pragma unroll
      for (int ni = 0; ni < 2; ++ni)
        b[kc][ni] = *(const i32x4*)(Bp + (wc * 64 + ni * 32 + l31) * 16);
    }
    asm volatile("s_waitcnt lgkmcnt(0)" ::: "memory");
    BARRIER();                           // all waves done reading buf -> free it
    if (t + 3 < NT) stage(buf, t + 3);   // loads overlap MFMA + next ~2 tiles

    __builtin_amdgcn_s_setprio(1);
#pragma unroll
    for (int kc = 0; kc < 2; ++kc)
#pragma unroll
      for (int mi = 0; mi < 4; ++mi)
#pragma unroll
        for (int ni = 0; ni < 2; ++ni)
          acc[mi][ni] = __builtin_amdgcn_mfma_i32_32x32x32_i8(a[kc][mi], b[kc][ni],
                                                              acc[mi][ni], 0, 0, 0);
    __builtin_amdgcn_s_setprio(0);

    buf = (buf == 2) ? 0 : buf + 1;
  }

  // epilogue: C/D layout col=lane&31, row=(r&3)+8*(r>>2)+4*(lane>>5)
  const float alpha = *alphaP;
  const int row0 = br * 256 + wr * 128 + 4 * kgl;
  const int col0 = bc * 256 + wc * 64 + l31;
#pragma unroll
  for (int ni = 0; ni < 2; ++ni) {
    const int col = col0 + ni * 32;
    const float bf = __half2float(bias[col]);
#pragma unroll
    for (int mi = 0; mi < 4; ++mi) {
#pragma unroll
      for (int r = 0; r < 16; ++r) {
        const int row = row0 + mi * 32 + (r & 3) + 8 * (r >> 2);
        out[(size_t)row * N + col] = ((float)acc[mi][ni][r] + bf) * alpha;
      }
    }
  }
}

extern "C" void kernel_launch(void* const* d_in, const int* in_sizes, int n_in,
                              void* d_out, int out_size, void* d_ws, size_t ws_size,
                              hipStream_t stream) {
  const int*    x     = (const int*)d_in[0];
  const int*    wgt   = (const int*)d_in[1];
  const __half* bias  = (const __half*)d_in[2];
  const float*  alpha = (const float*)d_in[3];
  float*        out   = (float*)d_out;

  // workspace: packed A (32 MB) + packed B (16 MB) = 48 MB
  unsigned char* wa = (unsigned char*)d_ws;
  unsigned char* wb = wa + (size_t)M * K;

  pack_x_kernel<<<(M * (size_t)K / 16) / 256, 256, 0, stream>>>(x, wa);
  pack_w_kernel<<<(N * (size_t)K / 16) / 256, 256, 0, stream>>>(wgt, wb);

  dim3 grid((M / BM) * (N / BN));   // 512 blocks
  gemm_i8<<<grid, 512, 0, stream>>>(wa, wb, bias, alpha, out);
}